// Round 3
// baseline (795.106 us; speedup 1.0000x reference)
//
#include <hip/hip_runtime.h>
#include <stdint.h>

#define BB   8
#define NN   2048
#define FIN  256
#define FOUT 128

// ---------------- stage 1: h = x@W (fp32), f1 = h@a1, f2 = h@a2 ------------
// Block = 2 x-rows, 256 threads: il = t>>7 (row), o = t&127 (output feature).
// x rows staged in LDS (broadcast reads); W reads coalesced across o and
// L2-resident (128 KB). Pure VALU, fp32 exact vs np reference.
__global__ __launch_bounds__(256) void gat_h(
        const float* __restrict__ x, const float* __restrict__ W,
        const float* __restrict__ a, float* __restrict__ h,
        float* __restrict__ f1, float* __restrict__ f2) {
    __shared__ float xs[2 * FIN];
    __shared__ float red1[4], red2[4];
    const int t    = threadIdx.x;
    const int row0 = blockIdx.x * 2;

    // stage 512 contiguous floats (2 rows) into LDS
    ((float2*)xs)[t] = ((const float2*)(x + (size_t)row0 * FIN))[t];
    __syncthreads();

    const int il = t >> 7;        // 0..1
    const int o  = t & 127;
    const float* xr = xs + il * FIN;
    float acc = 0.f;
#pragma unroll 8
    for (int k = 0; k < FIN; ++k)
        acc = fmaf(xr[k], W[(k << 7) + o], acc);

    h[(size_t)(row0 + il) * FOUT + o] = acc;

    float p1 = acc * a[o];
    float p2 = acc * a[FOUT + o];
#pragma unroll
    for (int s = 1; s < 64; s <<= 1) {
        p1 += __shfl_xor(p1, s);
        p2 += __shfl_xor(p2, s);
    }
    const int w = t >> 6;         // wave id 0..3; waves 2*il, 2*il+1 share a row
    if ((t & 63) == 0) { red1[w] = p1; red2[w] = p2; }
    __syncthreads();
    if (t < 2) {
        f1[row0 + t] = red1[2 * t] + red1[2 * t + 1];
        f2[row0 + t] = red2[2 * t] + red2[2 * t + 1];
    }
}

// ---------------- stage 2: masked softmax attention + ELU (pure VALU) ------
// Block = 16 rows of batch b (b = blockIdx%8 -> per-XCD L2 locality for h).
// Thread = (il = t>>4, o-octet = (t&15)*8). Every thread walks all 2048 j:
// p computed redundantly per o-group (broadcast loads), denominator falls out
// for free (no reduction). No softmax-max needed: logits bounded (~|13|),
// masked entries contribute exactly 0 (matches exp(-9e15 - max) == 0).
__global__ __launch_bounds__(256) void gat_attn(
        const int* __restrict__ adj, const float* __restrict__ h,
        const float* __restrict__ f1, const float* __restrict__ f2,
        float* __restrict__ out) {
    const int bk = blockIdx.x;          // 0..1023
    const int b  = bk & 7;
    const int i0 = (bk >> 3) << 4;      // 16 rows per block
    const int t  = threadIdx.x;
    const int il = t >> 4;              // 0..15
    const int o0 = (t & 15) << 3;       // 0..120

    const int    gi     = (b << 11) + i0 + il;
    const float  f1r    = f1[gi];
    const int*   adjrow = adj + ((size_t)gi << 11);
    const float* f2b    = f2 + (b << 11);
    const float* hb     = h + (((size_t)b << 11) << 7);   // b*2048*128

    float acc[8] = {0.f, 0.f, 0.f, 0.f, 0.f, 0.f, 0.f, 0.f};
    float ssum = 0.f;

    for (int jc = 0; jc < NN / 4; ++jc) {
        const int j = jc << 2;
        int4   a4 = *(const int4*)(adjrow + j);   // 16 lanes same addr: broadcast
        float4 fj = *(const float4*)(f2b + j);
        int   am[4] = {a4.x, a4.y, a4.z, a4.w};
        float fm[4] = {fj.x, fj.y, fj.z, fj.w};
#pragma unroll
        for (int u = 0; u < 4; ++u) {
            float e = f1r + fm[u];
            float p = (am[u] > 0) ? __expf(fmaxf(e, 0.2f * e)) : 0.f;
            ssum += p;
            const float* hr = hb + (((size_t)(j + u)) << 7) + o0;
            float4 h0 = *(const float4*)hr;
            float4 h1 = *(const float4*)(hr + 4);
            acc[0] = fmaf(p, h0.x, acc[0]);
            acc[1] = fmaf(p, h0.y, acc[1]);
            acc[2] = fmaf(p, h0.z, acc[2]);
            acc[3] = fmaf(p, h0.w, acc[3]);
            acc[4] = fmaf(p, h1.x, acc[4]);
            acc[5] = fmaf(p, h1.y, acc[5]);
            acc[6] = fmaf(p, h1.z, acc[6]);
            acc[7] = fmaf(p, h1.w, acc[7]);
        }
    }

    const float inv = 1.0f / ssum;
    float r[8];
#pragma unroll
    for (int d = 0; d < 8; ++d) {
        float y = acc[d] * inv;
        r[d] = (y > 0.f) ? y : expm1f(y);   // ELU, alpha=1
    }
    float* orow = out + ((size_t)gi << 7) + o0;
    float4 r0; r0.x = r[0]; r0.y = r[1]; r0.z = r[2]; r0.w = r[3];
    float4 r1; r1.x = r[4]; r1.y = r[5]; r1.z = r[6]; r1.w = r[7];
    *(float4*)(orow)     = r0;
    *(float4*)(orow + 4) = r1;
}

extern "C" void kernel_launch(void* const* d_in, const int* in_sizes, int n_in,
                              void* d_out, int out_size, void* d_ws, size_t ws_size,
                              hipStream_t stream) {
    // Identify inputs by element count (all four are distinct) — removes any
    // dependence on argument ordering.
    const float* x   = nullptr;
    const int*   adj = nullptr;
    const float* W   = nullptr;
    const float* a   = nullptr;
    for (int i = 0; i < n_in; ++i) {
        const long s = in_sizes[i];
        if      (s == (long)BB * NN * NN)  adj = (const int*)d_in[i];
        else if (s == (long)BB * NN * FIN) x   = (const float*)d_in[i];
        else if (s == (long)FIN * FOUT)    W   = (const float*)d_in[i];
        else if (s == 2L * FOUT)           a   = (const float*)d_in[i];
    }
    if (!x)   x   = (const float*)d_in[0];
    if (!adj) adj = (const int*)d_in[1];
    if (!W)   W   = (const float*)d_in[2];
    if (!a)   a   = (const float*)d_in[3];
    float* out = (float*)d_out;

    float* h  = (float*)d_ws;                        // 8 MB   h fp32 [B*N][FOUT]
    float* f1 = h + (size_t)BB * NN * FOUT;          // 64 KB
    float* f2 = f1 + BB * NN;                        // 64 KB

    hipLaunchKernelGGL(gat_h,    dim3(8192), dim3(256), 0, stream, x, W, a, h, f1, f2);
    hipLaunchKernelGGL(gat_attn, dim3(1024), dim3(256), 0, stream, adj, h, f1, f2, out);
}

// Round 4
// 333.372 us; speedup vs baseline: 2.3850x; 2.3850x over previous
//
#include <hip/hip_runtime.h>
#include <stdint.h>

#define BB   8
#define NN   2048
#define FIN  256
#define FOUT 128

using short8 = __attribute__((ext_vector_type(8))) short;
using f32x4  = __attribute__((ext_vector_type(4))) float;

__device__ __forceinline__ unsigned short rbf(float f) {
    return (unsigned short)((__float_as_uint(f) + 0x8000u) >> 16);
}

// ---------------- stage 1: h = x@W (fp32), f1/f2; h stored bf16 row-major --
// Identical compute to the validated round-3 kernel; only the h store dtype
// changed (fp32 -> bf16) to fit ws and feed the MFMA stage.
__global__ __launch_bounds__(256) void gat_h(
        const float* __restrict__ x, const float* __restrict__ W,
        const float* __restrict__ a, unsigned short* __restrict__ hb,
        float* __restrict__ f1, float* __restrict__ f2) {
    __shared__ float xs[2 * FIN];
    __shared__ float red1[4], red2[4];
    const int t    = threadIdx.x;
    const int row0 = blockIdx.x * 2;

    ((float2*)xs)[t] = ((const float2*)(x + (size_t)row0 * FIN))[t];
    __syncthreads();

    const int il = t >> 7;
    const int o  = t & 127;
    const float* xr = xs + il * FIN;
    float acc = 0.f;
#pragma unroll 8
    for (int k = 0; k < FIN; ++k)
        acc = fmaf(xr[k], W[(k << 7) + o], acc);

    hb[(size_t)(row0 + il) * FOUT + o] = rbf(acc);

    float p1 = acc * a[o];
    float p2 = acc * a[FOUT + o];
#pragma unroll
    for (int s = 1; s < 64; s <<= 1) {
        p1 += __shfl_xor(p1, s);
        p2 += __shfl_xor(p2, s);
    }
    const int w = t >> 6;
    if ((t & 63) == 0) { red1[w] = p1; red2[w] = p2; }
    __syncthreads();
    if (t < 2) {
        f1[row0 + t] = red1[2 * t] + red1[2 * t + 1];
        f2[row0 + t] = red2[2 * t] + red2[2 * t + 1];
    }
}

// ---------------- transpose: hb[i][o] bf16 -> ht[b][o][i] bf16 -------------
// 64x64 tiles via LDS. grid = 256 i-tiles x 2 o-tiles = 512 blocks.
__global__ __launch_bounds__(256) void gat_tr(
        const unsigned short* __restrict__ hb, unsigned short* __restrict__ ht) {
    __shared__ unsigned short tile[64][66];
    const int bi = blockIdx.x;
    const int ot = bi & 1;
    const int it = bi >> 1;
    const int i0 = it << 6;
    const int o0 = ot << 6;
    const int t  = threadIdx.x;

#pragma unroll
    for (int rr = 0; rr < 4; ++rr) {
        const int r = (t >> 4) + (rr << 4);
        const int c = (t & 15) << 2;
        ushort4 v = *(const ushort4*)(hb + (size_t)(i0 + r) * FOUT + o0 + c);
        tile[r][c + 0] = v.x; tile[r][c + 1] = v.y;
        tile[r][c + 2] = v.z; tile[r][c + 3] = v.w;
    }
    __syncthreads();

    const int b   = i0 >> 11;
    const int il0 = i0 & (NN - 1);
    const int oc  = t >> 2;          // 0..63
    const int is  = (t & 3) << 4;    // 0,16,32,48
    short8 v0, v1;
#pragma unroll
    for (int u = 0; u < 8; ++u) {
        v0[u] = (short)tile[is + u][oc];
        v1[u] = (short)tile[is + 8 + u][oc];
    }
    unsigned short* dst = ht + ((size_t)((b << 7) + o0 + oc) << 11) + il0 + is;
    *(short8*)(dst)     = v0;
    *(short8*)(dst + 8) = v1;
}

// ---------------- stage 2: fused masked-softmax attention (MFMA) -----------
// Self-calibrating: two probe MFMAs read off the true (i,o) label of each
// accumulator element, so the epilogue is correct under ANY C/D / B lane map.
__global__ __launch_bounds__(256) void gat_s2(
        const int* __restrict__ adj, const unsigned short* __restrict__ ht,
        const float* __restrict__ f1, const float* __restrict__ f2,
        float* __restrict__ out) {
    const int bk   = blockIdx.x;        // 0..1023
    const int b    = bk & 7;            // batch fastest -> per-XCD L2 locality
    const int i0   = (bk >> 3) << 4;
    const int tid  = threadIdx.x;
    const int w    = tid >> 6;
    const int lane = tid & 63;
    const int m    = lane & 15;
    const int quad = lane >> 4;

    __shared__ float sbuf[4][16];
    __shared__ float accbuf[4][16][128];

    // ---- calibration probes ----
    // probe1: A[r][k]=delta(k,k0) (all rows), B[k][n]=n  -> D[M][N]=N
    // probe2: A[r][k]=delta(k,k0)*r,          B[k][n]=1  -> D[M][N]=M
    short8 pa1, pb1, pa2, pb2;
    const short one = (short)0x3F80;                 // bf16 1.0
    const short mb  = (short)rbf((float)m);          // bf16 m (exact)
#pragma unroll
    for (int j = 0; j < 8; ++j) { pa1[j] = 0; pa2[j] = 0; pb1[j] = mb; pb2[j] = one; }
    if (quad == 0) { pa1[0] = one; pa2[0] = mb; }
    f32x4 zz = {0.f, 0.f, 0.f, 0.f};
    f32x4 c1 = __builtin_amdgcn_mfma_f32_16x16x32_bf16(pa1, pb1, zz, 0, 0, 0);
    f32x4 c2 = __builtin_amdgcn_mfma_f32_16x16x32_bf16(pa2, pb2, zz, 0, 0, 0);
    int oo[4], io[4];
#pragma unroll
    for (int r = 0; r < 4; ++r) {
        oo[r] = ((int)c1[r]) & 15;   // o-label (within 16) of acc element r
        io[r] = ((int)c2[r]) & 15;   // i-label of acc element r
    }

    const float f1r = f1[(b << 11) + i0 + m];
    const int*  adjrow = adj + ((size_t)((b << 11) + i0 + m) << 11);
    const float* f2b = f2 + (b << 11);
    const unsigned short* htb = ht + ((size_t)b << 18);

    f32x4 acc[8];
#pragma unroll
    for (int t2 = 0; t2 < 8; ++t2) acc[t2] = zz;
    float ssum = 0.f;

#pragma unroll 2
    for (int c = 0; c < 16; ++c) {
        const int j0 = (w << 9) + (c << 5) + (quad << 3);
        int4   aj0 = *(const int4*)(adjrow + j0);
        int4   aj1 = *(const int4*)(adjrow + j0 + 4);
        float4 fa  = *(const float4*)(f2b + j0);
        float4 fb  = *(const float4*)(f2b + j0 + 4);
        short8 hf[8];
#pragma unroll
        for (int ot = 0; ot < 8; ++ot)
            hf[ot] = *(const short8*)(htb + ((((ot << 4) + m) << 11) + j0));

        float p[8];
        {
            float t0 = f1r + fa.x, t1 = f1r + fa.y, t2 = f1r + fa.z, t3 = f1r + fa.w;
            float t4 = f1r + fb.x, t5 = f1r + fb.y, t6 = f1r + fb.z, t7 = f1r + fb.w;
            p[0] = (aj0.x > 0) ? __expf(fmaxf(t0, 0.2f * t0)) : 0.f;
            p[1] = (aj0.y > 0) ? __expf(fmaxf(t1, 0.2f * t1)) : 0.f;
            p[2] = (aj0.z > 0) ? __expf(fmaxf(t2, 0.2f * t2)) : 0.f;
            p[3] = (aj0.w > 0) ? __expf(fmaxf(t3, 0.2f * t3)) : 0.f;
            p[4] = (aj1.x > 0) ? __expf(fmaxf(t4, 0.2f * t4)) : 0.f;
            p[5] = (aj1.y > 0) ? __expf(fmaxf(t5, 0.2f * t5)) : 0.f;
            p[6] = (aj1.z > 0) ? __expf(fmaxf(t6, 0.2f * t6)) : 0.f;
            p[7] = (aj1.w > 0) ? __expf(fmaxf(t7, 0.2f * t7)) : 0.f;
        }
        ssum += ((p[0] + p[1]) + (p[2] + p[3])) + ((p[4] + p[5]) + (p[6] + p[7]));

        short8 pf;
        pf[0] = (short)rbf(p[0]); pf[1] = (short)rbf(p[1]);
        pf[2] = (short)rbf(p[2]); pf[3] = (short)rbf(p[3]);
        pf[4] = (short)rbf(p[4]); pf[5] = (short)rbf(p[5]);
        pf[6] = (short)rbf(p[6]); pf[7] = (short)rbf(p[7]);

#pragma unroll
        for (int ot = 0; ot < 8; ++ot)
            acc[ot] = __builtin_amdgcn_mfma_f32_16x16x32_bf16(pf, hf[ot], acc[ot], 0, 0, 0);
    }

    ssum += __shfl_xor(ssum, 16);
    ssum += __shfl_xor(ssum, 32);
    if (lane < 16) sbuf[w][lane] = ssum;
#pragma unroll
    for (int ot = 0; ot < 8; ++ot)
#pragma unroll
        for (int r = 0; r < 4; ++r)
            accbuf[w][io[r]][(ot << 4) + oo[r]] = acc[ot][r];
    __syncthreads();

    {
        const int row = tid >> 4;
        const int o0  = (tid & 15) << 3;
        float s = (sbuf[0][row] + sbuf[1][row]) + (sbuf[2][row] + sbuf[3][row]);
        float inv = 1.0f / s;
        float v[8];
#pragma unroll
        for (int d = 0; d < 8; ++d)
            v[d] = (accbuf[0][row][o0 + d] + accbuf[1][row][o0 + d]) +
                   (accbuf[2][row][o0 + d] + accbuf[3][row][o0 + d]);
        float4 r0, r1;
        float y;
        y = v[0] * inv; r0.x = y > 0.f ? y : expm1f(y);
        y = v[1] * inv; r0.y = y > 0.f ? y : expm1f(y);
        y = v[2] * inv; r0.z = y > 0.f ? y : expm1f(y);
        y = v[3] * inv; r0.w = y > 0.f ? y : expm1f(y);
        y = v[4] * inv; r1.x = y > 0.f ? y : expm1f(y);
        y = v[5] * inv; r1.y = y > 0.f ? y : expm1f(y);
        y = v[6] * inv; r1.z = y > 0.f ? y : expm1f(y);
        y = v[7] * inv; r1.w = y > 0.f ? y : expm1f(y);
        float* orow = out + (((size_t)(b << 11) + i0 + row) << 7) + o0;
        *(float4*)(orow)     = r0;
        *(float4*)(orow + 4) = r1;
    }
}

extern "C" void kernel_launch(void* const* d_in, const int* in_sizes, int n_in,
                              void* d_out, int out_size, void* d_ws, size_t ws_size,
                              hipStream_t stream) {
    const float* x   = nullptr;
    const int*   adj = nullptr;
    const float* W   = nullptr;
    const float* a   = nullptr;
    for (int i = 0; i < n_in; ++i) {
        const long s = in_sizes[i];
        if      (s == (long)BB * NN * NN)  adj = (const int*)d_in[i];
        else if (s == (long)BB * NN * FIN) x   = (const float*)d_in[i];
        else if (s == (long)FIN * FOUT)    W   = (const float*)d_in[i];
        else if (s == 2L * FOUT)           a   = (const float*)d_in[i];
    }
    if (!x)   x   = (const float*)d_in[0];
    if (!adj) adj = (const int*)d_in[1];
    if (!W)   W   = (const float*)d_in[2];
    if (!a)   a   = (const float*)d_in[3];
    float* out = (float*)d_out;

    unsigned short* hb = (unsigned short*)d_ws;            // 4 MB  h bf16 [B*N][128]
    unsigned short* ht = hb + (size_t)BB * NN * FOUT;      // 4 MB  h^T bf16 [B][128][N]
    float* f1 = (float*)(ht + (size_t)BB * NN * FOUT);     // 64 KB
    float* f2 = f1 + BB * NN;                              // 64 KB

    hipLaunchKernelGGL(gat_h,  dim3(8192), dim3(256), 0, stream, x, W, a, hb, f1, f2);
    hipLaunchKernelGGL(gat_tr, dim3(512),  dim3(256), 0, stream, hb, ht);
    hipLaunchKernelGGL(gat_s2, dim3(1024), dim3(256), 0, stream, adj, ht, f1, f2, out);
}

// Round 5
// 281.525 us; speedup vs baseline: 2.8243x; 1.1842x over previous
//
#include <hip/hip_runtime.h>
#include <stdint.h>

#define BB   8
#define NN   2048
#define FIN  256
#define FOUT 128

using short8 = __attribute__((ext_vector_type(8))) short;
using f32x4  = __attribute__((ext_vector_type(4))) float;

__device__ __forceinline__ unsigned short rbf(float f) {
    return (unsigned short)((__float_as_uint(f) + 0x8000u) >> 16);
}

// Calibration: 2 probe MFMAs read off the true (row,col) label of each
// accumulator element. Validated in round 4. Mlab = M(row)-label, Nlab = N(col).
__device__ __forceinline__ void mfma_calib(int m, int quad, int* Mlab, int* Nlab) {
    short8 pa1, pb1, pa2, pb2;
    const short one = (short)0x3F80;            // bf16 1.0
    const short mb  = (short)rbf((float)m);     // bf16 m (exact, m<16)
#pragma unroll
    for (int j = 0; j < 8; ++j) { pa1[j] = 0; pa2[j] = 0; pb1[j] = mb; pb2[j] = one; }
    if (quad == 0) { pa1[0] = one; pa2[0] = mb; }
    f32x4 zz = {0.f, 0.f, 0.f, 0.f};
    f32x4 c1 = __builtin_amdgcn_mfma_f32_16x16x32_bf16(pa1, pb1, zz, 0, 0, 0);
    f32x4 c2 = __builtin_amdgcn_mfma_f32_16x16x32_bf16(pa2, pb2, zz, 0, 0, 0);
#pragma unroll
    for (int r = 0; r < 4; ++r) {
        Nlab[r] = ((int)c1[r]) & 15;
        Mlab[r] = ((int)c2[r]) & 15;
    }
}

// ---------------- W[256][128] fp32 -> wt[128][256] bf16 (W^T) --------------
__global__ __launch_bounds__(256) void gat_wt(const float* __restrict__ W,
                                              unsigned short* __restrict__ wt) {
    const int g  = blockIdx.x * 256 + threadIdx.x;   // 0..8191
    const int k  = g >> 5;
    const int o4 = (g & 31) << 2;
    float4 wv = *(const float4*)(W + (k << 7) + o4);
    wt[((o4 + 0) << 8) + k] = rbf(wv.x);
    wt[((o4 + 1) << 8) + k] = rbf(wv.y);
    wt[((o4 + 2) << 8) + k] = rbf(wv.z);
    wt[((o4 + 3) << 8) + k] = rbf(wv.w);
}

// ---------------- stage 1: h = x@W via MFMA; f1/f2 fp32; ht[b][o][i] bf16 --
// A = x rows (M=i), B = wt rows (N=o), both in the round-4-validated lane
// conventions; C/D scattered to LDS via calibrated labels.
__global__ __launch_bounds__(256) void gat_h2(
        const float* __restrict__ x, const unsigned short* __restrict__ wt,
        const float* __restrict__ a, unsigned short* __restrict__ ht,
        float* __restrict__ f1, float* __restrict__ f2) {
    __shared__ float hs[64][129];
    const int tid  = threadIdx.x;
    const int w    = tid >> 6;
    const int lane = tid & 63;
    const int m    = lane & 15;
    const int quad = lane >> 4;
    const int R0   = blockIdx.x << 6;           // 64 rows/block
    const int gi   = R0 + (w << 4) + m;

    int Mlab[4], Nlab[4];
    mfma_calib(m, quad, Mlab, Nlab);

    f32x4 zz = {0.f, 0.f, 0.f, 0.f};
    f32x4 acc[8];
#pragma unroll
    for (int t = 0; t < 8; ++t) acc[t] = zz;

    const float* xrow = x + (size_t)gi * FIN;
#pragma unroll
    for (int kc = 0; kc < 8; ++kc) {
        const int k0 = (kc << 5) + (quad << 3);
        float4 xa = *(const float4*)(xrow + k0);
        float4 xb = *(const float4*)(xrow + k0 + 4);
        short8 av;
        av[0] = (short)rbf(xa.x); av[1] = (short)rbf(xa.y);
        av[2] = (short)rbf(xa.z); av[3] = (short)rbf(xa.w);
        av[4] = (short)rbf(xb.x); av[5] = (short)rbf(xb.y);
        av[6] = (short)rbf(xb.z); av[7] = (short)rbf(xb.w);
#pragma unroll
        for (int ot = 0; ot < 8; ++ot) {
            short8 bw = *(const short8*)(wt + ((((ot << 4) + m) << 8) + k0));
            acc[ot] = __builtin_amdgcn_mfma_f32_16x16x32_bf16(av, bw, acc[ot], 0, 0, 0);
        }
    }

    // scatter D to LDS by measured labels: hs[i_local][o]
#pragma unroll
    for (int ot = 0; ot < 8; ++ot)
#pragma unroll
        for (int r = 0; r < 4; ++r)
            hs[(w << 4) + Mlab[r]][(ot << 4) + Nlab[r]] = acc[ot][r];
    __syncthreads();

    // f1/f2 (fp32): thread -> (i = tid>>2, 32-o chunk = tid&3)
    {
        const int i  = tid >> 2;
        const int ch = (tid & 3) << 5;
        float s1 = 0.f, s2 = 0.f;
#pragma unroll
        for (int u = 0; u < 32; ++u) {
            float hv = hs[i][ch + u];
            s1 = fmaf(hv, a[ch + u], s1);
            s2 = fmaf(hv, a[FOUT + ch + u], s2);
        }
        s1 += __shfl_xor(s1, 1); s1 += __shfl_xor(s1, 2);
        s2 += __shfl_xor(s2, 1); s2 += __shfl_xor(s2, 2);
        if ((tid & 3) == 0) { f1[R0 + i] = s1; f2[R0 + i] = s2; }
    }

    // ht assembly: ht[b][o][i] bf16, coalesced short8 stores
    {
        const int b   = R0 >> 11;
        const int il0 = R0 & (NN - 1);
#pragma unroll
        for (int v = 0; v < 4; ++v) {
            const int u   = (v << 8) + tid;
            const int o   = u >> 3;
            const int io8 = (u & 7) << 3;
            short8 hv;
#pragma unroll
            for (int e = 0; e < 8; ++e) hv[e] = (short)rbf(hs[io8 + e][o]);
            *(short8*)(ht + ((size_t)((b << 7) + o) << 11) + il0 + io8) = hv;
        }
    }
}

// ---------------- stage 2: fused masked-softmax attention (MFMA) -----------
// Round-4-validated structure + explicit depth-1 adj/f2 prefetch and relaxed
// VGPR cap (LDS already limits to 4 blocks/CU, so 128 VGPRs are free).
__global__ __launch_bounds__(256, 4) void gat_s2(
        const int* __restrict__ adj, const unsigned short* __restrict__ ht,
        const float* __restrict__ f1, const float* __restrict__ f2,
        float* __restrict__ out) {
    const int bk   = blockIdx.x;        // 0..1023
    const int b    = bk & 7;            // batch fastest -> per-XCD L2 locality
    const int i0   = (bk >> 3) << 4;
    const int tid  = threadIdx.x;
    const int w    = tid >> 6;
    const int lane = tid & 63;
    const int m    = lane & 15;
    const int quad = lane >> 4;

    __shared__ float sbuf[4][16];
    __shared__ float accbuf[4][16][128];

    int Mlab[4], Nlab[4];
    mfma_calib(m, quad, Mlab, Nlab);

    const float f1r = f1[(b << 11) + i0 + m];
    const int*  adjrow = adj + ((size_t)((b << 11) + i0 + m) << 11);
    const float* f2b = f2 + (b << 11);
    const unsigned short* htb = ht + ((size_t)b << 18);

    f32x4 zz = {0.f, 0.f, 0.f, 0.f};
    f32x4 acc[8];
#pragma unroll
    for (int t2 = 0; t2 < 8; ++t2) acc[t2] = zz;
    float ssum = 0.f;

    const int jb = (w << 9) + (quad << 3);
    // prefetch c=0 adj/f2
    int4   aj0 = *(const int4*)(adjrow + jb);
    int4   aj1 = *(const int4*)(adjrow + jb + 4);
    float4 fa  = *(const float4*)(f2b + jb);
    float4 fb  = *(const float4*)(f2b + jb + 4);

#pragma unroll
    for (int c = 0; c < 16; ++c) {
        const int j0 = jb + (c << 5);
        // ht loads for this c — issue before the exp chain
        short8 hf[8];
#pragma unroll
        for (int ot = 0; ot < 8; ++ot)
            hf[ot] = *(const short8*)(htb + ((((ot << 4) + m) << 11) + j0));

        // prefetch next c's adj/f2 (in flight across exp+MFMA)
        int4 na0, na1; float4 nf0, nf1;
        if (c < 15) {
            na0 = *(const int4*)(adjrow + j0 + 32);
            na1 = *(const int4*)(adjrow + j0 + 36);
            nf0 = *(const float4*)(f2b + j0 + 32);
            nf1 = *(const float4*)(f2b + j0 + 36);
        }

        float p[8];
        {
            float t0 = f1r + fa.x, t1 = f1r + fa.y, t2 = f1r + fa.z, t3 = f1r + fa.w;
            float t4 = f1r + fb.x, t5 = f1r + fb.y, t6 = f1r + fb.z, t7 = f1r + fb.w;
            p[0] = (aj0.x > 0) ? __expf(fmaxf(t0, 0.2f * t0)) : 0.f;
            p[1] = (aj0.y > 0) ? __expf(fmaxf(t1, 0.2f * t1)) : 0.f;
            p[2] = (aj0.z > 0) ? __expf(fmaxf(t2, 0.2f * t2)) : 0.f;
            p[3] = (aj0.w > 0) ? __expf(fmaxf(t3, 0.2f * t3)) : 0.f;
            p[4] = (aj1.x > 0) ? __expf(fmaxf(t4, 0.2f * t4)) : 0.f;
            p[5] = (aj1.y > 0) ? __expf(fmaxf(t5, 0.2f * t5)) : 0.f;
            p[6] = (aj1.z > 0) ? __expf(fmaxf(t6, 0.2f * t6)) : 0.f;
            p[7] = (aj1.w > 0) ? __expf(fmaxf(t7, 0.2f * t7)) : 0.f;
        }
        ssum += ((p[0] + p[1]) + (p[2] + p[3])) + ((p[4] + p[5]) + (p[6] + p[7]));

        short8 pf;
        pf[0] = (short)rbf(p[0]); pf[1] = (short)rbf(p[1]);
        pf[2] = (short)rbf(p[2]); pf[3] = (short)rbf(p[3]);
        pf[4] = (short)rbf(p[4]); pf[5] = (short)rbf(p[5]);
        pf[6] = (short)rbf(p[6]); pf[7] = (short)rbf(p[7]);

#pragma unroll
        for (int ot = 0; ot < 8; ++ot)
            acc[ot] = __builtin_amdgcn_mfma_f32_16x16x32_bf16(pf, hf[ot], acc[ot], 0, 0, 0);

        if (c < 15) { aj0 = na0; aj1 = na1; fa = nf0; fb = nf1; }
    }

    ssum += __shfl_xor(ssum, 16);
    ssum += __shfl_xor(ssum, 32);
    if (lane < 16) sbuf[w][lane] = ssum;
#pragma unroll
    for (int ot = 0; ot < 8; ++ot)
#pragma unroll
        for (int r = 0; r < 4; ++r)
            accbuf[w][Mlab[r]][(ot << 4) + Nlab[r]] = acc[ot][r];
    __syncthreads();

    {
        const int row = tid >> 4;
        const int o0  = (tid & 15) << 3;
        float s = (sbuf[0][row] + sbuf[1][row]) + (sbuf[2][row] + sbuf[3][row]);
        float inv = 1.0f / s;
        float v[8];
#pragma unroll
        for (int d = 0; d < 8; ++d)
            v[d] = (accbuf[0][row][o0 + d] + accbuf[1][row][o0 + d]) +
                   (accbuf[2][row][o0 + d] + accbuf[3][row][o0 + d]);
        float4 r0, r1;
        float y;
        y = v[0] * inv; r0.x = y > 0.f ? y : expm1f(y);
        y = v[1] * inv; r0.y = y > 0.f ? y : expm1f(y);
        y = v[2] * inv; r0.z = y > 0.f ? y : expm1f(y);
        y = v[3] * inv; r0.w = y > 0.f ? y : expm1f(y);
        y = v[4] * inv; r1.x = y > 0.f ? y : expm1f(y);
        y = v[5] * inv; r1.y = y > 0.f ? y : expm1f(y);
        y = v[6] * inv; r1.z = y > 0.f ? y : expm1f(y);
        y = v[7] * inv; r1.w = y > 0.f ? y : expm1f(y);
        float* orow = out + (((size_t)(b << 11) + i0 + row) << 7) + o0;
        *(float4*)(orow)     = r0;
        *(float4*)(orow + 4) = r1;
    }
}

extern "C" void kernel_launch(void* const* d_in, const int* in_sizes, int n_in,
                              void* d_out, int out_size, void* d_ws, size_t ws_size,
                              hipStream_t stream) {
    const float* x   = nullptr;
    const int*   adj = nullptr;
    const float* W   = nullptr;
    const float* a   = nullptr;
    for (int i = 0; i < n_in; ++i) {
        const long s = in_sizes[i];
        if      (s == (long)BB * NN * NN)  adj = (const int*)d_in[i];
        else if (s == (long)BB * NN * FIN) x   = (const float*)d_in[i];
        else if (s == (long)FIN * FOUT)    W   = (const float*)d_in[i];
        else if (s == 2L * FOUT)           a   = (const float*)d_in[i];
    }
    if (!x)   x   = (const float*)d_in[0];
    if (!adj) adj = (const int*)d_in[1];
    if (!W)   W   = (const float*)d_in[2];
    if (!a)   a   = (const float*)d_in[3];
    float* out = (float*)d_out;

    unsigned short* wt = (unsigned short*)d_ws;            // 64 KB  W^T bf16
    unsigned short* ht = wt + 32768;                       // 4 MB   h^T bf16 [B][128][N]
    float* f1 = (float*)(ht + (size_t)BB * NN * FOUT);     // 64 KB
    float* f2 = f1 + BB * NN;                              // 64 KB

    hipLaunchKernelGGL(gat_wt, dim3(32),   dim3(256), 0, stream, W, wt);
    hipLaunchKernelGGL(gat_h2, dim3(256),  dim3(256), 0, stream, x, wt, a, ht, f1, f2);
    hipLaunchKernelGGL(gat_s2, dim3(1024), dim3(256), 0, stream, adj, ht, f1, f2, out);
}